// Round 2
// baseline (1014.932 us; speedup 1.0000x reference)
//
#include <hip/hip_runtime.h>

#define T_TOKENS 4096
#define HIDDEN   2048
#define INTERM   768
#define NE       8
#define NPAIR    8192   // T_TOKENS * TOP_K
#define NROT     4

typedef __bf16 bf16x8 __attribute__((ext_vector_type(8)));
typedef float  f32x4  __attribute__((ext_vector_type(4)));

__device__ __forceinline__ unsigned short f2bf(float f) {
  unsigned u = __float_as_uint(f);
  u += 0x7fffu + ((u >> 16) & 1u);   // round-to-nearest-even (finite inputs only)
  return (unsigned short)(u >> 16);
}

__device__ __forceinline__ void async16(const void* g, void* l) {
  __builtin_amdgcn_global_load_lds((const __attribute__((address_space(1))) void*)g,
                                   (__attribute__((address_space(3))) void*)l, 16, 0, 0);
}

// ---------------- routing: histogram / scan / scatter ----------------
__global__ void k_hist(const int* __restrict__ idx, int* __restrict__ cnt) {
  const int t = blockIdx.x * 256 + threadIdx.x;
  if (t < NPAIR) atomicAdd(&cnt[idx[t]], 1);
}

__global__ void k_scan(const int* __restrict__ cnt, int* __restrict__ off, int* __restrict__ cur) {
  if (threadIdx.x == 0) {
    int a = 0;
    for (int e = 0; e < NE; ++e) { off[e] = a; cur[e] = 0; a += cnt[e]; }
  }
}

__global__ void k_scatter(const int* __restrict__ idx, const float* __restrict__ wts,
                          const int* __restrict__ off, int* __restrict__ cur,
                          int* __restrict__ pt, float* __restrict__ pw) {
  const int t = blockIdx.x * 256 + threadIdx.x;
  if (t < NPAIR) {
    const int e = idx[t];
    const int pos = off[e] + atomicAdd(&cur[e], 1);
    pt[pos] = t >> 1;     // token id
    pw[pos] = wts[t];     // routing weight
  }
}

// ---------------- hidden_states fp32 -> bf16 ----------------
__global__ void k_cvt(const float4* __restrict__ X, ushort4* __restrict__ out) {
  const int t = blockIdx.x * 256 + threadIdx.x;
  const float4 v = X[t];
  ushort4 o;
  o.x = f2bf(v.x); o.y = f2bf(v.y); o.z = f2bf(v.z); o.w = f2bf(v.w);
  out[t] = o;
}

// ---------------- pseudo-quantize: one wave per (row, 128-col group) ----------------
__global__ void k_quant(const float* __restrict__ W, const int* __restrict__ pairs,
                        const float* __restrict__ angles, const float* __restrict__ ch,
                        unsigned short* __restrict__ out, int In, int G) {
  __shared__ float lw_all[4][128];
  const int wv = threadIdx.x >> 6, l = threadIdx.x & 63;
  const int gg = blockIdx.x * 4 + wv;         // global group id
  const int row = gg / G;
  const int g = gg - row * G;
  const int colbase = g << 7;
  float* lw = lw_all[wv];
  const size_t wbase = (size_t)row * In + colbase;
  const float c0 = ch[colbase + l], c1 = ch[colbase + 64 + l];
  {
#pragma clang fp contract(off)
    lw[l]      = W[wbase + l] * c0;
    lw[64 + l] = W[wbase + 64 + l] * c1;
  }
  __syncthreads();
  const int half = In >> 1;
  // forward rotations
  for (int r = 0; r < NROT; ++r) {
    const int2 pr = ((const int2*)(pairs + r * In + colbase))[l];
    const float a = angles[r * half + (colbase >> 1) + l];
    const float ca = cosf(a), sa = sinf(a);
    const float wi = lw[pr.x], wj = lw[pr.y];
    {
#pragma clang fp contract(off)
      lw[pr.x] = ca * wi - sa * wj;
      lw[pr.y] = sa * wi + ca * wj;
    }
    __syncthreads();
  }
  // fake quant (group of 128 = this wave's 2 elems/lane)
  float v0 = lw[l], v1 = lw[64 + l];
  float mn = fminf(v0, v1), mx = fmaxf(v0, v1);
  for (int o = 32; o > 0; o >>= 1) {
    mn = fminf(mn, __shfl_xor(mn, o));
    mx = fmaxf(mx, __shfl_xor(mx, o));
  }
  {
#pragma clang fp contract(off)
    const float scale = fmaxf(mx - mn, 1e-5f) / 15.0f;
    const float zero = rintf(-mn / scale);
    const float q0 = fminf(fmaxf(rintf(v0 / scale) + zero, 0.0f), 15.0f);
    const float q1 = fminf(fmaxf(rintf(v1 / scale) + zero, 0.0f), 15.0f);
    lw[l]      = (q0 - zero) * scale;
    lw[64 + l] = (q1 - zero) * scale;
  }
  __syncthreads();
  // inverse rotations (reverse order, negated angles)
  for (int r = NROT - 1; r >= 0; --r) {
    const int2 pr = ((const int2*)(pairs + r * In + colbase))[l];
    const float a = angles[r * half + (colbase >> 1) + l];
    const float ca = cosf(a), sa = sinf(a);
    const float wi = lw[pr.x], wj = lw[pr.y];
    {
#pragma clang fp contract(off)
      lw[pr.x] = ca * wi + sa * wj;   // c*wi - (-s)*wj
      lw[pr.y] = ca * wj - sa * wi;   // (-s)*wi + c*wj
    }
    __syncthreads();
  }
  out[wbase + l]      = f2bf(lw[l] / c0);
  out[wbase + 64 + l] = f2bf(lw[64 + l] / c1);
}

// ---------------- expert-segmented GEMM: C = A * B^T (m97 structure) ----------------
// MODE 0: A = x_bf (rows via pair_token), B = gup_bf[e] (1536 x 2048), C = h (row=pos, ld 1536)
// MODE 1: A = inter (row=pos, 768), B = dwn_bf[e] (2048 x 768), atomicAdd into out[token]
template <int MODE>
__launch_bounds__(256, 2)
__global__ void k_gemm(const unsigned short* __restrict__ A,
                       const unsigned short* __restrict__ Bw,
                       float* __restrict__ C,
                       const int* __restrict__ pt,
                       const int* __restrict__ off,
                       const int* __restrict__ cnt) {
  constexpr int K = MODE ? INTERM : HIDDEN;
  constexpr int N = MODE ? HIDDEN : 2 * INTERM;
  const int e = blockIdx.z;
  const int count = cnt[e];
  const int m0 = blockIdx.x * 128;
  if (m0 >= count) return;
  const int seg = off[e];
  const int n0 = blockIdx.y * 128;
  const unsigned short* Be = Bw + (size_t)e * N * K;

  __shared__ unsigned short As[128 * 32];
  __shared__ unsigned short Bs[128 * 32];

  const int tid = threadIdx.x;
  const int w = tid >> 6;
  const int l = tid & 63;
  // staging: chunk c = (q*4+w)*64 + l; row = c>>2; kchunk = (c&3)*8
  const int r0 = w * 16 + (l >> 2);
  const int r1 = r0 + 64;
  const int kco = (l & 3) * 8;

  int p0 = m0 + r0; if (p0 > count - 1) p0 = count - 1;
  int p1 = m0 + r1; if (p1 > count - 1) p1 = count - 1;
  size_t arow0, arow1;
  if (MODE == 0) { arow0 = pt[seg + p0]; arow1 = pt[seg + p1]; }
  else           { arow0 = (size_t)(seg + p0); arow1 = (size_t)(seg + p1); }
  const unsigned short* pa0 = A + arow0 * K + kco;
  const unsigned short* pa1 = A + arow1 * K + kco;
  const unsigned short* pb0 = Be + (size_t)(n0 + r0) * K + kco;
  const unsigned short* pb1 = Be + (size_t)(n0 + r1) * K + kco;
  unsigned short* la0 = &As[(w) * 512];
  unsigned short* la1 = &As[(w + 4) * 512];
  unsigned short* lb0 = &Bs[(w) * 512];
  unsigned short* lb1 = &Bs[(w + 4) * 512];

  const int ko = (l >> 4) * 8;
  const int mrow = (w & 1) * 64 + (l & 15);
  const int nrow = (w >> 1) * 64 + (l & 15);

  f32x4 acc[4][4];
#pragma unroll
  for (int i = 0; i < 4; ++i)
#pragma unroll
    for (int j = 0; j < 4; ++j) acc[i][j] = (f32x4)0.0f;

  for (int k0 = 0; k0 < K; k0 += 32) {
    __syncthreads();
    async16(pa0 + k0, la0);
    async16(pa1 + k0, la1);
    async16(pb0 + k0, lb0);
    async16(pb1 + k0, lb1);
    __syncthreads();
    bf16x8 af[4], bfr[4];
#pragma unroll
    for (int i = 0; i < 4; ++i)
      af[i] = *(const bf16x8*)&As[(mrow + i * 16) * 32 + ko];
#pragma unroll
    for (int j = 0; j < 4; ++j)
      bfr[j] = *(const bf16x8*)&Bs[(nrow + j * 16) * 32 + ko];
#pragma unroll
    for (int i = 0; i < 4; ++i)
#pragma unroll
      for (int j = 0; j < 4; ++j)
        acc[i][j] = __builtin_amdgcn_mfma_f32_16x16x32_bf16(af[i], bfr[j], acc[i][j], 0, 0, 0);
  }

  // C/D layout: col = lane&15 (n / B-operand), row = (lane>>4)*4 + reg (m / A-operand)
  const int mb = (w & 1) * 64 + (l >> 4) * 4;
  const int nb = n0 + (w >> 1) * 64 + (l & 15);
#pragma unroll
  for (int i = 0; i < 4; ++i) {
#pragma unroll
    for (int j = 0; j < 4; ++j) {
#pragma unroll
      for (int r = 0; r < 4; ++r) {
        const int mm = m0 + mb + i * 16 + r;
        if (mm < count) {
          const int nn = nb + j * 16;
          if (MODE == 0) {
            C[(size_t)(seg + mm) * N + nn] = acc[i][j][r];
          } else {
            atomicAdd(&C[(size_t)pt[seg + mm] * N + nn], acc[i][j][r]);
          }
        }
      }
    }
  }
}

// ---------------- silu(gate)*up * routing_weight -> bf16 ----------------
__global__ void k_silu(const float* __restrict__ h, const float* __restrict__ pw,
                       ushort4* __restrict__ inter) {
  const int t = blockIdx.x * 256 + threadIdx.x;     // NPAIR * 192 threads
  const int p = t / 192;
  const int i4 = (t - p * 192) * 4;
  const float4 g = *(const float4*)&h[(size_t)p * 1536 + i4];
  const float4 u = *(const float4*)&h[(size_t)p * 1536 + 768 + i4];
  const float wgt = pw[p];
  ushort4 o;
  o.x = f2bf(g.x / (1.0f + expf(-g.x)) * u.x * wgt);
  o.y = f2bf(g.y / (1.0f + expf(-g.y)) * u.y * wgt);
  o.z = f2bf(g.z / (1.0f + expf(-g.z)) * u.z * wgt);
  o.w = f2bf(g.w / (1.0f + expf(-g.w)) * u.w * wgt);
  inter[(size_t)p * 192 + (i4 >> 2)] = o;
}

// ---------------- launch ----------------
extern "C" void kernel_launch(void* const* d_in, const int* in_sizes, int n_in,
                              void* d_out, int out_size, void* d_ws, size_t ws_size,
                              hipStream_t stream) {
  const float* hs  = (const float*)d_in[0];
  const int*   tki = (const int*)d_in[1];
  const float* tkw = (const float*)d_in[2];
  const float* guw = (const float*)d_in[3];
  const float* dww = (const float*)d_in[4];
  const int*   gupr= (const int*)d_in[5];
  const float* gua = (const float*)d_in[6];
  const int*   dwp = (const int*)d_in[7];
  const float* dwa = (const float*)d_in[8];
  const float* gus = (const float*)d_in[9];
  const float* dwsc= (const float*)d_in[10];
  float* out = (float*)d_out;
  char* ws = (char*)d_ws;

  unsigned short* gup_bf = (unsigned short*)(ws + 0);          //  50,331,648 B
  unsigned short* dwn_bf = (unsigned short*)(ws + 50331648);   //  25,165,824 B
  unsigned short* x_bf   = (unsigned short*)(ws + 75497472);   //  16,777,216 B
  float*          hbuf   = (float*)(ws + 92274688);            //  50,331,648 B
  unsigned short* interb = (unsigned short*)(ws + 142606336);  //  12,582,912 B
  int*            pt     = (int*)(ws + 155189248);             //  32,768 B
  float*          pw     = (float*)(ws + 155222016);           //  32,768 B
  int*            cnt    = (int*)(ws + 155254784);             //  96 B (cnt/off/cur)
  int*            off    = cnt + 8;
  int*            cur    = cnt + 16;

  (void)hipMemsetAsync(d_out, 0, (size_t)T_TOKENS * HIDDEN * sizeof(float), stream);
  (void)hipMemsetAsync(cnt, 0, 96, stream);

  k_hist<<<32, 256, 0, stream>>>(tki, cnt);
  k_scan<<<1, 64, 0, stream>>>(cnt, off, cur);
  k_scatter<<<32, 256, 0, stream>>>(tki, tkw, off, cur, pt, pw);
  k_cvt<<<8192, 256, 0, stream>>>((const float4*)hs, (ushort4*)x_bf);
  k_quant<<<49152, 256, 0, stream>>>(guw, gupr, gua, gus, gup_bf, 2048, 16);
  k_quant<<<24576, 256, 0, stream>>>(dww, dwp, dwa, dwsc, dwn_bf, 768, 6);
  k_gemm<0><<<dim3(64, 12, 8), 256, 0, stream>>>(x_bf, gup_bf, hbuf, pt, off, cnt);
  k_silu<<<6144, 256, 0, stream>>>(hbuf, pw, (ushort4*)interb);
  k_gemm<1><<<dim3(64, 16, 8), 256, 0, stream>>>(interb, dwn_bf, out, pt, off, cnt);
}

// Round 3
// 709.814 us; speedup vs baseline: 1.4299x; 1.4299x over previous
//
#include <hip/hip_runtime.h>

#define T_TOKENS 4096
#define HIDDEN   2048
#define INTERM   768
#define NE       8
#define NPAIR    8192   // T_TOKENS * TOP_K
#define NROT     4
#define MAXT     72     // max total m-tiles across experts (sum ceil(cnt/128) <= 71)

typedef __bf16 bf16x8 __attribute__((ext_vector_type(8)));
typedef float  f32x4  __attribute__((ext_vector_type(4)));

// wave-local LDS fence: lanes are lockstep within a wave; this makes prior
// ds_writes visible to subsequent ds_reads without a block barrier.
#define WSYNC() asm volatile("s_waitcnt lgkmcnt(0)" ::: "memory")

__device__ __forceinline__ unsigned short f2bf(float f) {
  unsigned u = __float_as_uint(f);
  u += 0x7fffu + ((u >> 16) & 1u);   // round-to-nearest-even (finite inputs only)
  return (unsigned short)(u >> 16);
}

__device__ __forceinline__ void async16(const void* g, void* l) {
  __builtin_amdgcn_global_load_lds((const __attribute__((address_space(1))) void*)g,
                                   (__attribute__((address_space(3))) void*)l, 16, 0, 0);
}

// ---------------- routing: histogram / scan+tilemap / scatter ----------------
__global__ void k_hist(const int* __restrict__ idx, int* __restrict__ cnt) {
  const int t = blockIdx.x * 256 + threadIdx.x;
  if (t < NPAIR) atomicAdd(&cnt[idx[t]], 1);
}

__global__ void k_scan(const int* __restrict__ cnt, int* __restrict__ off,
                       int* __restrict__ cur, int* __restrict__ tmap) {
  if (threadIdx.x == 0) {
    int a = 0, tt = 0;
    for (int e = 0; e < NE; ++e) {
      off[e] = a; cur[e] = 0;
      const int c = cnt[e];
      for (int m = 0; m < c; m += 128) tmap[tt++] = (e << 16) | (m >> 7);
      a += c;
    }
    for (; tt < MAXT; ++tt) tmap[tt] = -1;
  }
}

__global__ void k_scatter(const int* __restrict__ idx, const float* __restrict__ wts,
                          const int* __restrict__ off, int* __restrict__ cur,
                          int* __restrict__ pt, float* __restrict__ pw) {
  const int t = blockIdx.x * 256 + threadIdx.x;
  if (t < NPAIR) {
    const int e = idx[t];
    const int pos = off[e] + atomicAdd(&cur[e], 1);
    pt[pos] = t >> 1;     // token id
    pw[pos] = wts[t];     // routing weight
  }
}

// ---------------- hidden_states fp32 -> bf16 ----------------
__global__ void k_cvt(const float4* __restrict__ X, ushort4* __restrict__ out) {
  const int t = blockIdx.x * 256 + threadIdx.x;
  const float4 v = X[t];
  ushort4 o;
  o.x = f2bf(v.x); o.y = f2bf(v.y); o.z = f2bf(v.z); o.w = f2bf(v.w);
  out[t] = o;
}

// ---------------- precompute cos/sin tables ----------------
__global__ void k_trig(const float* __restrict__ ga, const float* __restrict__ da,
                       float2* __restrict__ tg, float2* __restrict__ td) {
  const int i = blockIdx.x * 256 + threadIdx.x;
  if (i < NROT * (HIDDEN / 2)) { const float a = ga[i]; tg[i] = make_float2(cosf(a), sinf(a)); }
  if (i < NROT * (INTERM / 2)) { const float a = da[i]; td[i] = make_float2(cosf(a), sinf(a)); }
}

// ---------------- pseudo-quantize: one wave per (row, 128-col group) ----------------
__global__ void k_quant(const float* __restrict__ W, const int* __restrict__ pairs,
                        const float2* __restrict__ trig, const float* __restrict__ ch,
                        unsigned short* __restrict__ out, int In, int G) {
  __shared__ float lw_all[4][128];
  const int wv = threadIdx.x >> 6, l = threadIdx.x & 63;
  const int gg = blockIdx.x * 4 + wv;         // global group id
  const int row = gg / G;
  const int g = gg - row * G;
  const int colbase = g << 7;
  float* lw = lw_all[wv];
  const size_t wbase = (size_t)row * In + colbase;
  const float c0 = ch[colbase + l], c1 = ch[colbase + 64 + l];
  {
#pragma clang fp contract(off)
    lw[l]      = W[wbase + l] * c0;
    lw[64 + l] = W[wbase + 64 + l] * c1;
  }
  WSYNC();
  const int half = In >> 1;
  // forward rotations
  for (int r = 0; r < NROT; ++r) {
    const int2 pr = ((const int2*)(pairs + r * In + colbase))[l];
    const float2 cs = trig[r * half + (colbase >> 1) + l];
    const float wi = lw[pr.x], wj = lw[pr.y];
    {
#pragma clang fp contract(off)
      lw[pr.x] = cs.x * wi - cs.y * wj;
      lw[pr.y] = cs.y * wi + cs.x * wj;
    }
    WSYNC();
  }
  // fake quant (group of 128 = this wave's 2 elems/lane)
  float v0 = lw[l], v1 = lw[64 + l];
  float mn = fminf(v0, v1), mx = fmaxf(v0, v1);
  for (int o = 32; o > 0; o >>= 1) {
    mn = fminf(mn, __shfl_xor(mn, o));
    mx = fmaxf(mx, __shfl_xor(mx, o));
  }
  {
#pragma clang fp contract(off)
    const float scale = fmaxf(mx - mn, 1e-5f) / 15.0f;
    const float zero = rintf(-mn / scale);
    const float q0 = fminf(fmaxf(rintf(v0 / scale) + zero, 0.0f), 15.0f);
    const float q1 = fminf(fmaxf(rintf(v1 / scale) + zero, 0.0f), 15.0f);
    lw[l]      = (q0 - zero) * scale;
    lw[64 + l] = (q1 - zero) * scale;
  }
  WSYNC();
  // inverse rotations (reverse order, negated angles)
  for (int r = NROT - 1; r >= 0; --r) {
    const int2 pr = ((const int2*)(pairs + r * In + colbase))[l];
    const float2 cs = trig[r * half + (colbase >> 1) + l];
    const float wi = lw[pr.x], wj = lw[pr.y];
    {
#pragma clang fp contract(off)
      lw[pr.x] = cs.x * wi + cs.y * wj;   // c*wi - (-s)*wj
      lw[pr.y] = cs.x * wj - cs.y * wi;   // (-s)*wi + c*wj
    }
    WSYNC();
  }
  out[wbase + l]      = f2bf(lw[l] / c0);
  out[wbase + 64 + l] = f2bf(lw[64 + l] / c1);
}

// ---------------- expert-segmented GEMM: C = A * B^T, dbuf pipeline ----------------
// MODE 0: A = x_bf (rows via pair_token), B = gup_bf[e] (1536 x 2048), C = h (row=pos, ld 1536)
// MODE 1: A = inter (row=pos, 768), B = dwn_bf[e] (2048 x 768), atomicAdd into out[token]
template <int MODE>
__launch_bounds__(256, 3)
__global__ void k_gemm(const unsigned short* __restrict__ A,
                       const unsigned short* __restrict__ Bw,
                       float* __restrict__ C,
                       const int* __restrict__ pt,
                       const int* __restrict__ off,
                       const int* __restrict__ cnt,
                       const int* __restrict__ tmap) {
  constexpr int K = MODE ? INTERM : HIDDEN;
  constexpr int N = MODE ? HIDDEN : 2 * INTERM;
  const int tm = tmap[blockIdx.x];
  if (tm < 0) return;
  const int e = tm >> 16;
  const int m0 = (tm & 0xffff) << 7;
  const int count = cnt[e];
  const int seg = off[e];
  const int n0 = blockIdx.y * 128;
  const unsigned short* Be = Bw + (size_t)e * N * K;

  __shared__ unsigned short As[2][128 * 32];
  __shared__ unsigned short Bs[2][128 * 32];

  const int tid = threadIdx.x;
  const int w = tid >> 6;
  const int l = tid & 63;
  // staging: lane l of wave w covers row = w*16 + (l>>2) (+64), kchunk = (l&3)*8
  const int r0 = w * 16 + (l >> 2);
  const int r1 = r0 + 64;
  const int kco = (l & 3) * 8;

  int p0 = m0 + r0; if (p0 > count - 1) p0 = count - 1;
  int p1 = m0 + r1; if (p1 > count - 1) p1 = count - 1;
  size_t arow0, arow1;
  if (MODE == 0) { arow0 = pt[seg + p0]; arow1 = pt[seg + p1]; }
  else           { arow0 = (size_t)(seg + p0); arow1 = (size_t)(seg + p1); }
  const unsigned short* pa0 = A + arow0 * K + kco;
  const unsigned short* pa1 = A + arow1 * K + kco;
  const unsigned short* pb0 = Be + (size_t)(n0 + r0) * K + kco;
  const unsigned short* pb1 = Be + (size_t)(n0 + r1) * K + kco;

  const int ko = (l >> 4) * 8;
  const int mrow = (w & 1) * 64 + (l & 15);
  const int nrow = (w >> 1) * 64 + (l & 15);

  f32x4 acc[4][4];
#pragma unroll
  for (int i = 0; i < 4; ++i)
#pragma unroll
    for (int j = 0; j < 4; ++j) acc[i][j] = (f32x4)0.0f;

  // prologue: stage tile 0 into buffer 0
  {
    async16(pa0, &As[0][w * 512]);
    async16(pa1, &As[0][(w + 4) * 512]);
    async16(pb0, &Bs[0][w * 512]);
    async16(pb1, &Bs[0][(w + 4) * 512]);
  }
  int buf = 0;
  for (int k0 = 0; k0 < K; k0 += 32, buf ^= 1) {
    __syncthreads();               // drains this buf's loads (vmcnt(0) before barrier)
    if (k0 + 32 < K) {             // prefetch next tile into the other buffer
      const int kn = k0 + 32;
      async16(pa0 + kn, &As[buf ^ 1][w * 512]);
      async16(pa1 + kn, &As[buf ^ 1][(w + 4) * 512]);
      async16(pb0 + kn, &Bs[buf ^ 1][w * 512]);
      async16(pb1 + kn, &Bs[buf ^ 1][(w + 4) * 512]);
    }
    bf16x8 af[4], bfr[4];
#pragma unroll
    for (int i = 0; i < 4; ++i)
      af[i] = *(const bf16x8*)&As[buf][(mrow + i * 16) * 32 + ko];
#pragma unroll
    for (int j = 0; j < 4; ++j)
      bfr[j] = *(const bf16x8*)&Bs[buf][(nrow + j * 16) * 32 + ko];
#pragma unroll
    for (int i = 0; i < 4; ++i)
#pragma unroll
      for (int j = 0; j < 4; ++j)
        acc[i][j] = __builtin_amdgcn_mfma_f32_16x16x32_bf16(af[i], bfr[j], acc[i][j], 0, 0, 0);
  }

  // C/D layout: col = lane&15 (n), row = (lane>>4)*4 + reg (m)
  const int mb = (w & 1) * 64 + (l >> 4) * 4;
  const int nb = n0 + (w >> 1) * 64 + (l & 15);
#pragma unroll
  for (int i = 0; i < 4; ++i) {
#pragma unroll
    for (int j = 0; j < 4; ++j) {
#pragma unroll
      for (int r = 0; r < 4; ++r) {
        const int mm = m0 + mb + i * 16 + r;
        if (mm < count) {
          const int nn = nb + j * 16;
          if (MODE == 0) {
            C[(size_t)(seg + mm) * N + nn] = acc[i][j][r];
          } else {
            atomicAdd(&C[(size_t)pt[seg + mm] * N + nn], acc[i][j][r]);
          }
        }
      }
    }
  }
}

// ---------------- silu(gate)*up * routing_weight -> bf16 ----------------
__global__ void k_silu(const float* __restrict__ h, const float* __restrict__ pw,
                       ushort4* __restrict__ inter) {
  const int t = blockIdx.x * 256 + threadIdx.x;     // NPAIR * 192 threads
  const int p = t / 192;
  const int i4 = (t - p * 192) * 4;
  const float4 g = *(const float4*)&h[(size_t)p * 1536 + i4];
  const float4 u = *(const float4*)&h[(size_t)p * 1536 + 768 + i4];
  const float wgt = pw[p];
  ushort4 o;
  o.x = f2bf(g.x / (1.0f + expf(-g.x)) * u.x * wgt);
  o.y = f2bf(g.y / (1.0f + expf(-g.y)) * u.y * wgt);
  o.z = f2bf(g.z / (1.0f + expf(-g.z)) * u.z * wgt);
  o.w = f2bf(g.w / (1.0f + expf(-g.w)) * u.w * wgt);
  inter[(size_t)p * 192 + (i4 >> 2)] = o;
}

// ---------------- launch ----------------
extern "C" void kernel_launch(void* const* d_in, const int* in_sizes, int n_in,
                              void* d_out, int out_size, void* d_ws, size_t ws_size,
                              hipStream_t stream) {
  const float* hs  = (const float*)d_in[0];
  const int*   tki = (const int*)d_in[1];
  const float* tkw = (const float*)d_in[2];
  const float* guw = (const float*)d_in[3];
  const float* dww = (const float*)d_in[4];
  const int*   gupr= (const int*)d_in[5];
  const float* gua = (const float*)d_in[6];
  const int*   dwp = (const int*)d_in[7];
  const float* dwa = (const float*)d_in[8];
  const float* gus = (const float*)d_in[9];
  const float* dwsc= (const float*)d_in[10];
  float* out = (float*)d_out;
  char* ws = (char*)d_ws;

  unsigned short* gup_bf = (unsigned short*)(ws + 0);          //  50,331,648 B
  unsigned short* dwn_bf = (unsigned short*)(ws + 50331648);   //  25,165,824 B
  unsigned short* x_bf   = (unsigned short*)(ws + 75497472);   //  16,777,216 B
  float*          hbuf   = (float*)(ws + 92274688);            //  50,331,648 B
  unsigned short* interb = (unsigned short*)(ws + 142606336);  //  12,582,912 B
  int*            pt     = (int*)(ws + 155189248);             //  32,768 B
  float*          pw     = (float*)(ws + 155222016);           //  32,768 B
  int*            cnt    = (int*)(ws + 155254784);             //  cnt/off/cur/tmap
  int*            off    = cnt + 8;
  int*            cur    = cnt + 16;
  int*            tmap   = cnt + 24;
  // trig tables live at the START of hbuf's region: written by k_trig, read by
  // k_quant, then overwritten by k_gemm<0>'s output (strictly later in-stream).
  float2*         tg     = (float2*)hbuf;                      // 4*1024 float2
  float2*         td     = tg + NROT * (HIDDEN / 2);           // 4*384  float2

  (void)hipMemsetAsync(d_out, 0, (size_t)T_TOKENS * HIDDEN * sizeof(float), stream);
  (void)hipMemsetAsync(cnt, 0, 32, stream);

  k_hist<<<32, 256, 0, stream>>>(tki, cnt);
  k_scan<<<1, 64, 0, stream>>>(cnt, off, cur, tmap);
  k_scatter<<<32, 256, 0, stream>>>(tki, tkw, off, cur, pt, pw);
  k_cvt<<<8192, 256, 0, stream>>>((const float4*)hs, (ushort4*)x_bf);
  k_trig<<<16, 256, 0, stream>>>(gua, dwa, tg, td);
  k_quant<<<49152, 256, 0, stream>>>(guw, gupr, tg, gus, gup_bf, 2048, 16);
  k_quant<<<24576, 256, 0, stream>>>(dww, dwp, td, dwsc, dwn_bf, 768, 6);
  k_gemm<0><<<dim3(MAXT, 12), 256, 0, stream>>>(x_bf, gup_bf, hbuf, pt, off, cnt, tmap);
  k_silu<<<6144, 256, 0, stream>>>(hbuf, pw, (ushort4*)interb);
  k_gemm<1><<<dim3(MAXT, 16), 256, 0, stream>>>(interb, dwn_bf, out, pt, off, cnt, tmap);
}

// Round 4
// 660.106 us; speedup vs baseline: 1.5375x; 1.0753x over previous
//
#include <hip/hip_runtime.h>

#define T_TOKENS 4096
#define HIDDEN   2048
#define INTERM   768
#define NE       8
#define NPAIR    8192   // T_TOKENS * TOP_K
#define NROT     4
#define MAXT     72     // max total m-tiles across experts

typedef __bf16 bf16x8 __attribute__((ext_vector_type(8)));
typedef float  f32x4  __attribute__((ext_vector_type(4)));

__device__ __forceinline__ unsigned short f2bf(float f) {
  unsigned u = __float_as_uint(f);
  u += 0x7fffu + ((u >> 16) & 1u);   // round-to-nearest-even (finite inputs only)
  return (unsigned short)(u >> 16);
}

__device__ __forceinline__ void async16(const void* g, void* l) {
  __builtin_amdgcn_global_load_lds((const __attribute__((address_space(1))) void*)g,
                                   (__attribute__((address_space(3))) void*)l, 16, 0, 0);
}

// ---------------- routing: histogram / scan+tilemap / scatter ----------------
__global__ void k_hist(const int* __restrict__ idx, int* __restrict__ cnt) {
  const int t = blockIdx.x * 256 + threadIdx.x;
  if (t < NPAIR) atomicAdd(&cnt[idx[t]], 1);
}

__global__ void k_scan(const int* __restrict__ cnt, int* __restrict__ off,
                       int* __restrict__ cur, int* __restrict__ tmap) {
  if (threadIdx.x == 0) {
    int a = 0, tt = 0;
    for (int e = 0; e < NE; ++e) {
      off[e] = a; cur[e] = 0;
      const int c = cnt[e];
      for (int m = 0; m < c; m += 128) tmap[tt++] = (e << 16) | (m >> 7);
      a += c;
    }
    for (; tt < MAXT; ++tt) tmap[tt] = -1;
  }
}

__global__ void k_scatter(const int* __restrict__ idx, const float* __restrict__ wts,
                          const int* __restrict__ off, int* __restrict__ cur,
                          int* __restrict__ pt, float* __restrict__ pw) {
  const int t = blockIdx.x * 256 + threadIdx.x;
  if (t < NPAIR) {
    const int e = idx[t];
    const int pos = off[e] + atomicAdd(&cur[e], 1);
    pt[pos] = t >> 1;     // token id
    pw[pos] = wts[t];     // routing weight
  }
}

// ---------------- hidden_states fp32 -> bf16 ----------------
__global__ void k_cvt(const float4* __restrict__ X, ushort4* __restrict__ out) {
  const int t = blockIdx.x * 256 + threadIdx.x;
  const float4 v = X[t];
  ushort4 o;
  o.x = f2bf(v.x); o.y = f2bf(v.y); o.z = f2bf(v.z); o.w = f2bf(v.w);
  out[t] = o;
}

// ---------------- build per-destination rotation tables + recip channel scales ----
// tbl entry for (group g, rot r, dest d in [0,128)): {cos, signed_sin, partner_bits, 0}
// forward:  new[d] = cos*old[d] + signed_sin*old[p]
// inverse:  new[d] = cos*old[d] - signed_sin*old[p]
__global__ void k_tbl(const int* __restrict__ gp, const float* __restrict__ ga,
                      const int* __restrict__ dp, const float* __restrict__ da,
                      const float* __restrict__ gch, const float* __restrict__ dch,
                      float4* __restrict__ tg, float4* __restrict__ td,
                      float* __restrict__ grch, float* __restrict__ drch) {
  const int t = blockIdx.x * 256 + threadIdx.x;
  if (t < NROT * (HIDDEN / 2)) {
    const int r = t >> 10, s = t & 1023;          // slot s over 1024 pairs
    const int grp = s >> 6;
    const int i = gp[r * HIDDEN + 2 * s], j = gp[r * HIDDEN + 2 * s + 1];
    const float a = ga[r * (HIDDEN / 2) + s];
    const float c = cosf(a), sn = sinf(a);
    tg[(grp * NROT + r) * 128 + i] = make_float4(c, -sn, __int_as_float(j), 0.f);
    tg[(grp * NROT + r) * 128 + j] = make_float4(c,  sn, __int_as_float(i), 0.f);
  }
  if (t < NROT * (INTERM / 2)) {
    const int r = t / (INTERM / 2), s = t - r * (INTERM / 2);
    const int grp = s >> 6;
    const int i = dp[r * INTERM + 2 * s], j = dp[r * INTERM + 2 * s + 1];
    const float a = da[r * (INTERM / 2) + s];
    const float c = cosf(a), sn = sinf(a);
    td[(grp * NROT + r) * 128 + i] = make_float4(c, -sn, __int_as_float(j), 0.f);
    td[(grp * NROT + r) * 128 + j] = make_float4(c,  sn, __int_as_float(i), 0.f);
  }
  if (t < HIDDEN) grch[t] = 1.0f / gch[t];
  if (t < INTERM) drch[t] = 1.0f / dch[t];
}

// ---------------- pseudo-quantize: register-resident, bpermute gathers ----------
// block = 4 waves, one group g, 16 rows (4 per wave). No data in LDS; only the
// 8 KB table is staged once. grid.x = (rows/16) * G, g cycles fastest.
__global__ __launch_bounds__(256) void k_quant(
    const float* __restrict__ W, const float4* __restrict__ tbl,
    const float* __restrict__ ch, const float* __restrict__ rch,
    unsigned short* __restrict__ out, int In, int G) {
  __shared__ float4 tl[NROT * 128];
  const int wv = threadIdx.x >> 6, l = threadIdx.x & 63;
  const int g = blockIdx.x % G;
  const int rowblk = blockIdx.x / G;
  const int row0 = rowblk * 16 + wv * 4;
  const int colbase = g << 7;
  tl[threadIdx.x]       = tbl[(size_t)g * NROT * 128 + threadIdx.x];
  tl[256 + threadIdx.x] = tbl[(size_t)g * NROT * 128 + 256 + threadIdx.x];
  __syncthreads();
  const float c0 = ch[colbase + l], c1 = ch[colbase + 64 + l];
  const float i0 = rch[colbase + l], i1 = rch[colbase + 64 + l];
  float v0[4], v1[4];
#pragma unroll
  for (int q = 0; q < 4; ++q) {
#pragma clang fp contract(off)
    const float* Wr = W + (size_t)(row0 + q) * In + colbase;
    v0[q] = Wr[l] * c0;
    v1[q] = Wr[64 + l] * c1;
  }
  // forward rotations
#pragma unroll
  for (int r = 0; r < NROT; ++r) {
    const float4 e0 = tl[r * 128 + l];
    const float4 e1 = tl[r * 128 + 64 + l];
    const int p0 = __float_as_int(e0.z), p1 = __float_as_int(e1.z);
    const int a0 = (p0 & 63) << 2, a1 = (p1 & 63) << 2;
#pragma unroll
    for (int q = 0; q < 4; ++q) {
      const int x0 = __float_as_int(v0[q]), x1 = __float_as_int(v1[q]);
      const float lo0 = __int_as_float(__builtin_amdgcn_ds_bpermute(a0, x0));
      const float hi0 = __int_as_float(__builtin_amdgcn_ds_bpermute(a0, x1));
      const float lo1 = __int_as_float(__builtin_amdgcn_ds_bpermute(a1, x0));
      const float hi1 = __int_as_float(__builtin_amdgcn_ds_bpermute(a1, x1));
      const float op0 = (p0 & 64) ? hi0 : lo0;
      const float op1 = (p1 & 64) ? hi1 : lo1;
      {
#pragma clang fp contract(off)
        v0[q] = e0.x * v0[q] + e0.y * op0;
        v1[q] = e1.x * v1[q] + e1.y * op1;
      }
    }
  }
  // fake quant per row (group of 128 = v0,v1 across the wave)
#pragma unroll
  for (int q = 0; q < 4; ++q) {
    float mn = fminf(v0[q], v1[q]), mx = fmaxf(v0[q], v1[q]);
#pragma unroll
    for (int o = 32; o > 0; o >>= 1) {
      mn = fminf(mn, __shfl_xor(mn, o));
      mx = fmaxf(mx, __shfl_xor(mx, o));
    }
    {
#pragma clang fp contract(off)
      const float scale = fmaxf(mx - mn, 1e-5f) / 15.0f;
      const float zero = rintf(-mn / scale);
      const float q0 = fminf(fmaxf(rintf(v0[q] / scale) + zero, 0.0f), 15.0f);
      const float q1 = fminf(fmaxf(rintf(v1[q] / scale) + zero, 0.0f), 15.0f);
      v0[q] = (q0 - zero) * scale;
      v1[q] = (q1 - zero) * scale;
    }
  }
  // inverse rotations (reverse order; sin term sign-flipped)
#pragma unroll
  for (int r = NROT - 1; r >= 0; --r) {
    const float4 e0 = tl[r * 128 + l];
    const float4 e1 = tl[r * 128 + 64 + l];
    const int p0 = __float_as_int(e0.z), p1 = __float_as_int(e1.z);
    const int a0 = (p0 & 63) << 2, a1 = (p1 & 63) << 2;
#pragma unroll
    for (int q = 0; q < 4; ++q) {
      const int x0 = __float_as_int(v0[q]), x1 = __float_as_int(v1[q]);
      const float lo0 = __int_as_float(__builtin_amdgcn_ds_bpermute(a0, x0));
      const float hi0 = __int_as_float(__builtin_amdgcn_ds_bpermute(a0, x1));
      const float lo1 = __int_as_float(__builtin_amdgcn_ds_bpermute(a1, x0));
      const float hi1 = __int_as_float(__builtin_amdgcn_ds_bpermute(a1, x1));
      const float op0 = (p0 & 64) ? hi0 : lo0;
      const float op1 = (p1 & 64) ? hi1 : lo1;
      {
#pragma clang fp contract(off)
        v0[q] = e0.x * v0[q] - e0.y * op0;
        v1[q] = e1.x * v1[q] - e1.y * op1;
      }
    }
  }
#pragma unroll
  for (int q = 0; q < 4; ++q) {
    unsigned short* Or = out + (size_t)(row0 + q) * In + colbase;
    Or[l]      = f2bf(v0[q] * i0);
    Or[64 + l] = f2bf(v1[q] * i1);
  }
}

// ---------------- expert-segmented GEMM: C = A * B^T, dbuf pipeline ----------------
template <int MODE>
__launch_bounds__(256, 3)
__global__ void k_gemm(const unsigned short* __restrict__ A,
                       const unsigned short* __restrict__ Bw,
                       float* __restrict__ C,
                       const int* __restrict__ pt,
                       const int* __restrict__ off,
                       const int* __restrict__ cnt,
                       const int* __restrict__ tmap) {
  constexpr int K = MODE ? INTERM : HIDDEN;
  constexpr int N = MODE ? HIDDEN : 2 * INTERM;
  const int tm = tmap[blockIdx.x];
  if (tm < 0) return;
  const int e = tm >> 16;
  const int m0 = (tm & 0xffff) << 7;
  const int count = cnt[e];
  const int seg = off[e];
  const int n0 = blockIdx.y * 128;
  const unsigned short* Be = Bw + (size_t)e * N * K;

  __shared__ unsigned short As[2][128 * 32];
  __shared__ unsigned short Bs[2][128 * 32];

  const int tid = threadIdx.x;
  const int w = tid >> 6;
  const int l = tid & 63;
  const int r0 = w * 16 + (l >> 2);
  const int r1 = r0 + 64;
  const int kco = (l & 3) * 8;

  int p0 = m0 + r0; if (p0 > count - 1) p0 = count - 1;
  int p1 = m0 + r1; if (p1 > count - 1) p1 = count - 1;
  size_t arow0, arow1;
  if (MODE == 0) { arow0 = pt[seg + p0]; arow1 = pt[seg + p1]; }
  else           { arow0 = (size_t)(seg + p0); arow1 = (size_t)(seg + p1); }
  const unsigned short* pa0 = A + arow0 * K + kco;
  const unsigned short* pa1 = A + arow1 * K + kco;
  const unsigned short* pb0 = Be + (size_t)(n0 + r0) * K + kco;
  const unsigned short* pb1 = Be + (size_t)(n0 + r1) * K + kco;

  const int ko = (l >> 4) * 8;
  const int mrow = (w & 1) * 64 + (l & 15);
  const int nrow = (w >> 1) * 64 + (l & 15);

  f32x4 acc[4][4];
#pragma unroll
  for (int i = 0; i < 4; ++i)
#pragma unroll
    for (int j = 0; j < 4; ++j) acc[i][j] = (f32x4)0.0f;

  {
    async16(pa0, &As[0][w * 512]);
    async16(pa1, &As[0][(w + 4) * 512]);
    async16(pb0, &Bs[0][w * 512]);
    async16(pb1, &Bs[0][(w + 4) * 512]);
  }
  int buf = 0;
  for (int k0 = 0; k0 < K; k0 += 32, buf ^= 1) {
    __syncthreads();
    if (k0 + 32 < K) {
      const int kn = k0 + 32;
      async16(pa0 + kn, &As[buf ^ 1][w * 512]);
      async16(pa1 + kn, &As[buf ^ 1][(w + 4) * 512]);
      async16(pb0 + kn, &Bs[buf ^ 1][w * 512]);
      async16(pb1 + kn, &Bs[buf ^ 1][(w + 4) * 512]);
    }
    bf16x8 af[4], bfr[4];
#pragma unroll
    for (int i = 0; i < 4; ++i)
      af[i] = *(const bf16x8*)&As[buf][(mrow + i * 16) * 32 + ko];
#pragma unroll
    for (int j = 0; j < 4; ++j)
      bfr[j] = *(const bf16x8*)&Bs[buf][(nrow + j * 16) * 32 + ko];
#pragma unroll
    for (int i = 0; i < 4; ++i)
#pragma unroll
      for (int j = 0; j < 4; ++j)
        acc[i][j] = __builtin_amdgcn_mfma_f32_16x16x32_bf16(af[i], bfr[j], acc[i][j], 0, 0, 0);
  }

  const int mb = (w & 1) * 64 + (l >> 4) * 4;
  const int nb = n0 + (w >> 1) * 64 + (l & 15);
#pragma unroll
  for (int i = 0; i < 4; ++i) {
#pragma unroll
    for (int j = 0; j < 4; ++j) {
#pragma unroll
      for (int r = 0; r < 4; ++r) {
        const int mm = m0 + mb + i * 16 + r;
        if (mm < count) {
          const int nn = nb + j * 16;
          if (MODE == 0) {
            C[(size_t)(seg + mm) * N + nn] = acc[i][j][r];
          } else {
            atomicAdd(&C[(size_t)pt[seg + mm] * N + nn], acc[i][j][r]);
          }
        }
      }
    }
  }
}

// ---------------- silu(gate)*up * routing_weight -> bf16 ----------------
__global__ void k_silu(const float* __restrict__ h, const float* __restrict__ pw,
                       ushort4* __restrict__ inter) {
  const int t = blockIdx.x * 256 + threadIdx.x;     // NPAIR * 192 threads
  const int p = t / 192;
  const int i4 = (t - p * 192) * 4;
  const float4 g = *(const float4*)&h[(size_t)p * 1536 + i4];
  const float4 u = *(const float4*)&h[(size_t)p * 1536 + 768 + i4];
  const float wgt = pw[p];
  ushort4 o;
  o.x = f2bf(g.x / (1.0f + expf(-g.x)) * u.x * wgt);
  o.y = f2bf(g.y / (1.0f + expf(-g.y)) * u.y * wgt);
  o.z = f2bf(g.z / (1.0f + expf(-g.z)) * u.z * wgt);
  o.w = f2bf(g.w / (1.0f + expf(-g.w)) * u.w * wgt);
  inter[(size_t)p * 192 + (i4 >> 2)] = o;
}

// ---------------- launch ----------------
extern "C" void kernel_launch(void* const* d_in, const int* in_sizes, int n_in,
                              void* d_out, int out_size, void* d_ws, size_t ws_size,
                              hipStream_t stream) {
  const float* hs  = (const float*)d_in[0];
  const int*   tki = (const int*)d_in[1];
  const float* tkw = (const float*)d_in[2];
  const float* guw = (const float*)d_in[3];
  const float* dww = (const float*)d_in[4];
  const int*   gupr= (const int*)d_in[5];
  const float* gua = (const float*)d_in[6];
  const int*   dwp = (const int*)d_in[7];
  const float* dwa = (const float*)d_in[8];
  const float* gus = (const float*)d_in[9];
  const float* dwsc= (const float*)d_in[10];
  float* out = (float*)d_out;
  char* ws = (char*)d_ws;

  unsigned short* gup_bf = (unsigned short*)(ws + 0);          //  50,331,648 B
  unsigned short* dwn_bf = (unsigned short*)(ws + 50331648);   //  25,165,824 B
  unsigned short* x_bf   = (unsigned short*)(ws + 75497472);   //  16,777,216 B
  float*          hbuf   = (float*)(ws + 92274688);            //  50,331,648 B
  unsigned short* interb = (unsigned short*)(ws + 142606336);  //  12,582,912 B
  int*            pt     = (int*)(ws + 155189248);             //  32,768 B
  float*          pw     = (float*)(ws + 155222016);           //  32,768 B
  int*            cnt    = (int*)(ws + 155254784);             //  cnt/off/cur/tmap (384 B)
  int*            off    = cnt + 8;
  int*            cur    = cnt + 16;
  int*            tmap   = cnt + 24;
  float4*         tg     = (float4*)(ws + 155258880);          // 131,072 B (16 grp)
  float4*         td     = (float4*)(ws + 155389952);          //  49,152 B (6 grp)
  float*          grch   = (float*)(ws + 155439104);           //   8,192 B
  float*          drch   = (float*)(ws + 155447296);           //   3,072 B

  (void)hipMemsetAsync(d_out, 0, (size_t)T_TOKENS * HIDDEN * sizeof(float), stream);
  (void)hipMemsetAsync(cnt, 0, 32, stream);

  k_hist<<<32, 256, 0, stream>>>(tki, cnt);
  k_scan<<<1, 64, 0, stream>>>(cnt, off, cur, tmap);
  k_scatter<<<32, 256, 0, stream>>>(tki, tkw, off, cur, pt, pw);
  k_cvt<<<8192, 256, 0, stream>>>((const float4*)hs, (ushort4*)x_bf);
  k_tbl<<<16, 256, 0, stream>>>(gupr, gua, dwp, dwa, gus, dwsc, tg, td, grch, drch);
  k_quant<<<12288, 256, 0, stream>>>(guw, tg, gus, grch, gup_bf, HIDDEN, 16);
  k_quant<<<6144, 256, 0, stream>>>(dww, td, dwsc, drch, dwn_bf, INTERM, 6);
  k_gemm<0><<<dim3(MAXT, 12), 256, 0, stream>>>(x_bf, gup_bf, hbuf, pt, off, cnt, tmap);
  k_silu<<<6144, 256, 0, stream>>>(hbuf, pw, (ushort4*)interb);
  k_gemm<1><<<dim3(MAXT, 16), 256, 0, stream>>>(interb, dwn_bf, out, pt, off, cnt, tmap);
}

// Round 5
// 624.502 us; speedup vs baseline: 1.6252x; 1.0570x over previous
//
#include <hip/hip_runtime.h>

#define T_TOKENS 4096
#define HIDDEN   2048
#define INTERM   768
#define NE       8
#define NPAIR    8192   // T_TOKENS * TOP_K
#define NROT     4
#define MAXT     72     // max total m-tiles across experts

typedef __bf16 bf16x8 __attribute__((ext_vector_type(8)));
typedef float  f32x4  __attribute__((ext_vector_type(4)));

__device__ __forceinline__ unsigned short f2bf(float f) {
  unsigned u = __float_as_uint(f);
  u += 0x7fffu + ((u >> 16) & 1u);   // round-to-nearest-even (finite inputs only)
  return (unsigned short)(u >> 16);
}

__device__ __forceinline__ void async16(const void* g, void* l) {
  __builtin_amdgcn_global_load_lds((const __attribute__((address_space(1))) void*)g,
                                   (__attribute__((address_space(3))) void*)l, 16, 0, 0);
}

// ---------------- routing: histogram / scan+tilemap / scatter ----------------
__global__ void k_hist(const int* __restrict__ idx, int* __restrict__ cnt) {
  const int t = blockIdx.x * 256 + threadIdx.x;
  if (t < NPAIR) atomicAdd(&cnt[idx[t]], 1);
}

__global__ void k_scan(const int* __restrict__ cnt, int* __restrict__ off,
                       int* __restrict__ cur, int* __restrict__ tmap) {
  if (threadIdx.x == 0) {
    int a = 0, tt = 0;
    for (int e = 0; e < NE; ++e) {
      off[e] = a; cur[e] = 0;
      const int c = cnt[e];
      for (int m = 0; m < c; m += 128) tmap[tt++] = (e << 16) | (m >> 7);
      a += c;
    }
    for (; tt < MAXT; ++tt) tmap[tt] = -1;
  }
}

__global__ void k_scatter(const int* __restrict__ idx, const float* __restrict__ wts,
                          const int* __restrict__ off, int* __restrict__ cur,
                          int* __restrict__ pt, float* __restrict__ pw) {
  const int t = blockIdx.x * 256 + threadIdx.x;
  if (t < NPAIR) {
    const int e = idx[t];
    const int pos = off[e] + atomicAdd(&cur[e], 1);
    pt[pos] = t >> 1;     // token id
    pw[pos] = wts[t];     // routing weight
  }
}

// ---------------- hidden_states fp32 -> bf16 ----------------
__global__ void k_cvt(const float4* __restrict__ X, ushort4* __restrict__ out) {
  const int t = blockIdx.x * 256 + threadIdx.x;
  const float4 v = X[t];
  ushort4 o;
  o.x = f2bf(v.x); o.y = f2bf(v.y); o.z = f2bf(v.z); o.w = f2bf(v.w);
  out[t] = o;
}

// ---------------- build per-destination rotation tables + recip channel scales ----
__global__ void k_tbl(const int* __restrict__ gp, const float* __restrict__ ga,
                      const int* __restrict__ dp, const float* __restrict__ da,
                      const float* __restrict__ gch, const float* __restrict__ dch,
                      float4* __restrict__ tg, float4* __restrict__ td,
                      float* __restrict__ grch, float* __restrict__ drch) {
  const int t = blockIdx.x * 256 + threadIdx.x;
  if (t < NROT * (HIDDEN / 2)) {
    const int r = t >> 10, s = t & 1023;          // slot s over 1024 pairs
    const int grp = s >> 6;
    const int i = gp[r * HIDDEN + 2 * s], j = gp[r * HIDDEN + 2 * s + 1];
    const float a = ga[r * (HIDDEN / 2) + s];
    const float c = cosf(a), sn = sinf(a);
    tg[(grp * NROT + r) * 128 + i] = make_float4(c, -sn, __int_as_float(j), 0.f);
    tg[(grp * NROT + r) * 128 + j] = make_float4(c,  sn, __int_as_float(i), 0.f);
  }
  if (t < NROT * (INTERM / 2)) {
    const int r = t / (INTERM / 2), s = t - r * (INTERM / 2);
    const int grp = s >> 6;
    const int i = dp[r * INTERM + 2 * s], j = dp[r * INTERM + 2 * s + 1];
    const float a = da[r * (INTERM / 2) + s];
    const float c = cosf(a), sn = sinf(a);
    td[(grp * NROT + r) * 128 + i] = make_float4(c, -sn, __int_as_float(j), 0.f);
    td[(grp * NROT + r) * 128 + j] = make_float4(c,  sn, __int_as_float(i), 0.f);
  }
  if (t < HIDDEN) grch[t] = 1.0f / gch[t];
  if (t < INTERM) drch[t] = 1.0f / dch[t];
}

// ---------------- pseudo-quantize: register-resident, bpermute gathers ----------
__global__ __launch_bounds__(256) void k_quant(
    const float* __restrict__ W, const float4* __restrict__ tbl,
    const float* __restrict__ ch, const float* __restrict__ rch,
    unsigned short* __restrict__ out, int In, int G) {
  __shared__ float4 tl[NROT * 128];
  const int wv = threadIdx.x >> 6, l = threadIdx.x & 63;
  const int g = blockIdx.x % G;
  const int rowblk = blockIdx.x / G;
  const int row0 = rowblk * 16 + wv * 4;
  const int colbase = g << 7;
  tl[threadIdx.x]       = tbl[(size_t)g * NROT * 128 + threadIdx.x];
  tl[256 + threadIdx.x] = tbl[(size_t)g * NROT * 128 + 256 + threadIdx.x];
  __syncthreads();
  const float c0 = ch[colbase + l], c1 = ch[colbase + 64 + l];
  const float i0 = rch[colbase + l], i1 = rch[colbase + 64 + l];
  float v0[4], v1[4];
#pragma unroll
  for (int q = 0; q < 4; ++q) {
#pragma clang fp contract(off)
    const float* Wr = W + (size_t)(row0 + q) * In + colbase;
    v0[q] = Wr[l] * c0;
    v1[q] = Wr[64 + l] * c1;
  }
  // forward rotations
#pragma unroll
  for (int r = 0; r < NROT; ++r) {
    const float4 e0 = tl[r * 128 + l];
    const float4 e1 = tl[r * 128 + 64 + l];
    const int p0 = __float_as_int(e0.z), p1 = __float_as_int(e1.z);
    const int a0 = (p0 & 63) << 2, a1 = (p1 & 63) << 2;
#pragma unroll
    for (int q = 0; q < 4; ++q) {
      const int x0 = __float_as_int(v0[q]), x1 = __float_as_int(v1[q]);
      const float lo0 = __int_as_float(__builtin_amdgcn_ds_bpermute(a0, x0));
      const float hi0 = __int_as_float(__builtin_amdgcn_ds_bpermute(a0, x1));
      const float lo1 = __int_as_float(__builtin_amdgcn_ds_bpermute(a1, x0));
      const float hi1 = __int_as_float(__builtin_amdgcn_ds_bpermute(a1, x1));
      const float op0 = (p0 & 64) ? hi0 : lo0;
      const float op1 = (p1 & 64) ? hi1 : lo1;
      {
#pragma clang fp contract(off)
        v0[q] = e0.x * v0[q] + e0.y * op0;
        v1[q] = e1.x * v1[q] + e1.y * op1;
      }
    }
  }
  // fake quant per row
#pragma unroll
  for (int q = 0; q < 4; ++q) {
    float mn = fminf(v0[q], v1[q]), mx = fmaxf(v0[q], v1[q]);
#pragma unroll
    for (int o = 32; o > 0; o >>= 1) {
      mn = fminf(mn, __shfl_xor(mn, o));
      mx = fmaxf(mx, __shfl_xor(mx, o));
    }
    {
#pragma clang fp contract(off)
      const float scale = fmaxf(mx - mn, 1e-5f) / 15.0f;
      const float zero = rintf(-mn / scale);
      const float q0 = fminf(fmaxf(rintf(v0[q] / scale) + zero, 0.0f), 15.0f);
      const float q1 = fminf(fmaxf(rintf(v1[q] / scale) + zero, 0.0f), 15.0f);
      v0[q] = (q0 - zero) * scale;
      v1[q] = (q1 - zero) * scale;
    }
  }
  // inverse rotations
#pragma unroll
  for (int r = NROT - 1; r >= 0; --r) {
    const float4 e0 = tl[r * 128 + l];
    const float4 e1 = tl[r * 128 + 64 + l];
    const int p0 = __float_as_int(e0.z), p1 = __float_as_int(e1.z);
    const int a0 = (p0 & 63) << 2, a1 = (p1 & 63) << 2;
#pragma unroll
    for (int q = 0; q < 4; ++q) {
      const int x0 = __float_as_int(v0[q]), x1 = __float_as_int(v1[q]);
      const float lo0 = __int_as_float(__builtin_amdgcn_ds_bpermute(a0, x0));
      const float hi0 = __int_as_float(__builtin_amdgcn_ds_bpermute(a0, x1));
      const float lo1 = __int_as_float(__builtin_amdgcn_ds_bpermute(a1, x0));
      const float hi1 = __int_as_float(__builtin_amdgcn_ds_bpermute(a1, x1));
      const float op0 = (p0 & 64) ? hi0 : lo0;
      const float op1 = (p1 & 64) ? hi1 : lo1;
      {
#pragma clang fp contract(off)
        v0[q] = e0.x * v0[q] - e0.y * op0;
        v1[q] = e1.x * v1[q] - e1.y * op1;
      }
    }
  }
#pragma unroll
  for (int q = 0; q < 4; ++q) {
    unsigned short* Or = out + (size_t)(row0 + q) * In + colbase;
    Or[l]      = f2bf(v0[q] * i0);
    Or[64 + l] = f2bf(v1[q] * i1);
  }
}

// ---------------- expert-segmented GEMM: C = A * B^T, dbuf pipeline ----------------
// grid = (n_tiles, MAXT): blockIdx.x = n-tile (fast dim) so B-panel sharers
// (same expert/n, consecutive m) sit 12/16 ids apart -> 2 XCDs, better L2 reuse.
// K-loop order: ds_read(current buf) FIRST, then issue prefetch into other buf,
// then MFMA — so the compiler never needs a vmcnt wait before the ds_reads.
template <int MODE>
__launch_bounds__(256, 4)
__global__ void k_gemm(const unsigned short* __restrict__ A,
                       const unsigned short* __restrict__ Bw,
                       float* __restrict__ C,
                       const int* __restrict__ pt,
                       const int* __restrict__ off,
                       const int* __restrict__ cnt,
                       const int* __restrict__ tmap) {
  constexpr int K = MODE ? INTERM : HIDDEN;
  constexpr int N = MODE ? HIDDEN : 2 * INTERM;
  const int tm = tmap[blockIdx.y];
  if (tm < 0) return;
  const int e = tm >> 16;
  const int m0 = (tm & 0xffff) << 7;
  const int count = cnt[e];
  const int seg = off[e];
  const int n0 = blockIdx.x * 128;
  const unsigned short* Be = Bw + (size_t)e * N * K;

  __shared__ unsigned short As[2][128 * 32];
  __shared__ unsigned short Bs[2][128 * 32];

  const int tid = threadIdx.x;
  const int w = tid >> 6;
  const int l = tid & 63;
  const int r0 = w * 16 + (l >> 2);
  const int r1 = r0 + 64;
  const int kco = (l & 3) * 8;

  int p0 = m0 + r0; if (p0 > count - 1) p0 = count - 1;
  int p1 = m0 + r1; if (p1 > count - 1) p1 = count - 1;
  size_t arow0, arow1;
  if (MODE == 0) { arow0 = pt[seg + p0]; arow1 = pt[seg + p1]; }
  else           { arow0 = (size_t)(seg + p0); arow1 = (size_t)(seg + p1); }
  const unsigned short* pa0 = A + arow0 * K + kco;
  const unsigned short* pa1 = A + arow1 * K + kco;
  const unsigned short* pb0 = Be + (size_t)(n0 + r0) * K + kco;
  const unsigned short* pb1 = Be + (size_t)(n0 + r1) * K + kco;

  const int ko = (l >> 4) * 8;
  const int mrow = (w & 1) * 64 + (l & 15);
  const int nrow = (w >> 1) * 64 + (l & 15);

  f32x4 acc[4][4];
#pragma unroll
  for (int i = 0; i < 4; ++i)
#pragma unroll
    for (int j = 0; j < 4; ++j) acc[i][j] = (f32x4)0.0f;

  {
    async16(pa0, &As[0][w * 512]);
    async16(pa1, &As[0][(w + 4) * 512]);
    async16(pb0, &Bs[0][w * 512]);
    async16(pb1, &Bs[0][(w + 4) * 512]);
  }
  int buf = 0;
  for (int k0 = 0; k0 < K; k0 += 32, buf ^= 1) {
    __syncthreads();               // drains the loads targeting 'buf'
    bf16x8 af[4], bfr[4];
#pragma unroll
    for (int i = 0; i < 4; ++i)
      af[i] = *(const bf16x8*)&As[buf][(mrow + i * 16) * 32 + ko];
#pragma unroll
    for (int j = 0; j < 4; ++j)
      bfr[j] = *(const bf16x8*)&Bs[buf][(nrow + j * 16) * 32 + ko];
    if (k0 + 32 < K) {             // prefetch next tile AFTER the ds_reads
      const int kn = k0 + 32;
      async16(pa0 + kn, &As[buf ^ 1][w * 512]);
      async16(pa1 + kn, &As[buf ^ 1][(w + 4) * 512]);
      async16(pb0 + kn, &Bs[buf ^ 1][w * 512]);
      async16(pb1 + kn, &Bs[buf ^ 1][(w + 4) * 512]);
    }
#pragma unroll
    for (int i = 0; i < 4; ++i)
#pragma unroll
      for (int j = 0; j < 4; ++j)
        acc[i][j] = __builtin_amdgcn_mfma_f32_16x16x32_bf16(af[i], bfr[j], acc[i][j], 0, 0, 0);
  }

  const int mb = (w & 1) * 64 + (l >> 4) * 4;
  const int nb = n0 + (w >> 1) * 64 + (l & 15);
#pragma unroll
  for (int i = 0; i < 4; ++i) {
#pragma unroll
    for (int j = 0; j < 4; ++j) {
#pragma unroll
      for (int r = 0; r < 4; ++r) {
        const int mm = m0 + mb + i * 16 + r;
        if (mm < count) {
          const int nn = nb + j * 16;
          if (MODE == 0) {
            C[(size_t)(seg + mm) * N + nn] = acc[i][j][r];
          } else {
            atomicAdd(&C[(size_t)pt[seg + mm] * N + nn], acc[i][j][r]);
          }
        }
      }
    }
  }
}

// ---------------- silu(gate)*up * routing_weight -> bf16 ----------------
__global__ void k_silu(const float* __restrict__ h, const float* __restrict__ pw,
                       ushort4* __restrict__ inter) {
  const int t = blockIdx.x * 256 + threadIdx.x;     // NPAIR * 192 threads
  const int p = t / 192;
  const int i4 = (t - p * 192) * 4;
  const float4 g = *(const float4*)&h[(size_t)p * 1536 + i4];
  const float4 u = *(const float4*)&h[(size_t)p * 1536 + 768 + i4];
  const float wgt = pw[p];
  ushort4 o;
  o.x = f2bf(g.x / (1.0f + expf(-g.x)) * u.x * wgt);
  o.y = f2bf(g.y / (1.0f + expf(-g.y)) * u.y * wgt);
  o.z = f2bf(g.z / (1.0f + expf(-g.z)) * u.z * wgt);
  o.w = f2bf(g.w / (1.0f + expf(-g.w)) * u.w * wgt);
  inter[(size_t)p * 192 + (i4 >> 2)] = o;
}

// ---------------- launch ----------------
extern "C" void kernel_launch(void* const* d_in, const int* in_sizes, int n_in,
                              void* d_out, int out_size, void* d_ws, size_t ws_size,
                              hipStream_t stream) {
  const float* hs  = (const float*)d_in[0];
  const int*   tki = (const int*)d_in[1];
  const float* tkw = (const float*)d_in[2];
  const float* guw = (const float*)d_in[3];
  const float* dww = (const float*)d_in[4];
  const int*   gupr= (const int*)d_in[5];
  const float* gua = (const float*)d_in[6];
  const int*   dwp = (const int*)d_in[7];
  const float* dwa = (const float*)d_in[8];
  const float* gus = (const float*)d_in[9];
  const float* dwsc= (const float*)d_in[10];
  float* out = (float*)d_out;
  char* ws = (char*)d_ws;

  unsigned short* gup_bf = (unsigned short*)(ws + 0);          //  50,331,648 B
  unsigned short* dwn_bf = (unsigned short*)(ws + 50331648);   //  25,165,824 B
  unsigned short* x_bf   = (unsigned short*)(ws + 75497472);   //  16,777,216 B
  float*          hbuf   = (float*)(ws + 92274688);            //  50,331,648 B
  unsigned short* interb = (unsigned short*)(ws + 142606336);  //  12,582,912 B
  int*            pt     = (int*)(ws + 155189248);             //  32,768 B
  float*          pw     = (float*)(ws + 155222016);           //  32,768 B
  int*            cnt    = (int*)(ws + 155254784);             //  cnt/off/cur/tmap (384 B)
  int*            off    = cnt + 8;
  int*            cur    = cnt + 16;
  int*            tmap   = cnt + 24;
  float4*         tg     = (float4*)(ws + 155258880);          // 131,072 B (16 grp)
  float4*         td     = (float4*)(ws + 155389952);          //  49,152 B (6 grp)
  float*          grch   = (float*)(ws + 155439104);           //   8,192 B
  float*          drch   = (float*)(ws + 155447296);           //   3,072 B

  (void)hipMemsetAsync(d_out, 0, (size_t)T_TOKENS * HIDDEN * sizeof(float), stream);
  (void)hipMemsetAsync(cnt, 0, 32, stream);

  k_hist<<<32, 256, 0, stream>>>(tki, cnt);
  k_scan<<<1, 64, 0, stream>>>(cnt, off, cur, tmap);
  k_scatter<<<32, 256, 0, stream>>>(tki, tkw, off, cur, pt, pw);
  k_cvt<<<8192, 256, 0, stream>>>((const float4*)hs, (ushort4*)x_bf);
  k_tbl<<<16, 256, 0, stream>>>(gupr, gua, dwp, dwa, gus, dwsc, tg, td, grch, drch);
  k_quant<<<12288, 256, 0, stream>>>(guw, tg, gus, grch, gup_bf, HIDDEN, 16);
  k_quant<<<6144, 256, 0, stream>>>(dww, td, dwsc, drch, dwn_bf, INTERM, 6);
  k_gemm<0><<<dim3(12, MAXT), 256, 0, stream>>>(x_bf, gup_bf, hbuf, pt, off, cnt, tmap);
  k_silu<<<6144, 256, 0, stream>>>(hbuf, pw, (ushort4*)interb);
  k_gemm<1><<<dim3(16, MAXT), 256, 0, stream>>>(interb, dwn_bf, out, pt, off, cnt, tmap);
}

// Round 6
// 581.531 us; speedup vs baseline: 1.7453x; 1.0739x over previous
//
#include <hip/hip_runtime.h>

#define T_TOKENS 4096
#define HIDDEN   2048
#define INTERM   768
#define NE       8
#define NPAIR    8192   // T_TOKENS * TOP_K
#define NROT     4
#define MAXT     72     // max total m-tiles across experts

typedef __bf16 bf16x8 __attribute__((ext_vector_type(8)));
typedef float  f32x4  __attribute__((ext_vector_type(4)));

__device__ __forceinline__ unsigned short f2bf(float f) {
  unsigned u = __float_as_uint(f);
  u += 0x7fffu + ((u >> 16) & 1u);   // round-to-nearest-even (finite inputs only)
  return (unsigned short)(u >> 16);
}

__device__ __forceinline__ void async16(const void* g, void* l) {
  __builtin_amdgcn_global_load_lds((const __attribute__((address_space(1))) void*)g,
                                   (__attribute__((address_space(3))) void*)l, 16, 0, 0);
}

// ---------------- routing: histogram / scan+tilemap / scatter ----------------
__global__ void k_hist(const int* __restrict__ idx, int* __restrict__ cnt) {
  const int t = blockIdx.x * 256 + threadIdx.x;
  if (t < NPAIR) atomicAdd(&cnt[idx[t]], 1);
}

__global__ void k_scan(const int* __restrict__ cnt, int* __restrict__ off,
                       int* __restrict__ cur, int* __restrict__ tmap) {
  if (threadIdx.x == 0) {
    int a = 0, tt = 0;
    for (int e = 0; e < NE; ++e) {
      off[e] = a; cur[e] = 0;
      const int c = cnt[e];
      for (int m = 0; m < c; m += 128) tmap[tt++] = (e << 16) | (m >> 7);
      a += c;
    }
    for (; tt < MAXT; ++tt) tmap[tt] = -1;
  }
}

__global__ void k_scatter(const int* __restrict__ idx, const float* __restrict__ wts,
                          const int* __restrict__ off, int* __restrict__ cur,
                          int* __restrict__ pt, float* __restrict__ pw) {
  const int t = blockIdx.x * 256 + threadIdx.x;
  if (t < NPAIR) {
    const int e = idx[t];
    const int pos = off[e] + atomicAdd(&cur[e], 1);
    pt[pos] = t >> 1;     // token id
    pw[pos] = wts[t];     // routing weight
  }
}

// ---------------- build per-destination rotation tables + recip channel scales ----
// entry (group g, rot r, dest d): {cos, signed_sin, partner, 0};
// forward: new[d] = cos*old[d] + signed_sin*old[partner]
__global__ void k_tbl(const int* __restrict__ gp, const float* __restrict__ ga,
                      const int* __restrict__ dp, const float* __restrict__ da,
                      const float* __restrict__ gch, const float* __restrict__ dch,
                      float4* __restrict__ tg, float4* __restrict__ td,
                      float* __restrict__ grch, float* __restrict__ drch) {
  const int t = blockIdx.x * 256 + threadIdx.x;
  if (t < NROT * (HIDDEN / 2)) {
    const int r = t >> 10, s = t & 1023;          // slot s over 1024 pairs
    const int grp = s >> 6;
    const int i = gp[r * HIDDEN + 2 * s], j = gp[r * HIDDEN + 2 * s + 1];
    const float a = ga[r * (HIDDEN / 2) + s];
    const float c = cosf(a), sn = sinf(a);
    tg[(grp * NROT + r) * 128 + i] = make_float4(c, -sn, __int_as_float(j), 0.f);
    tg[(grp * NROT + r) * 128 + j] = make_float4(c,  sn, __int_as_float(i), 0.f);
  }
  if (t < NROT * (INTERM / 2)) {
    const int r = t / (INTERM / 2), s = t - r * (INTERM / 2);
    const int grp = s >> 6;
    const int i = dp[r * INTERM + 2 * s], j = dp[r * INTERM + 2 * s + 1];
    const float a = da[r * (INTERM / 2) + s];
    const float c = cosf(a), sn = sinf(a);
    td[(grp * NROT + r) * 128 + i] = make_float4(c, -sn, __int_as_float(j), 0.f);
    td[(grp * NROT + r) * 128 + j] = make_float4(c,  sn, __int_as_float(i), 0.f);
  }
  if (t < HIDDEN) grch[t] = 1.0f / gch[t];
  if (t < INTERM) drch[t] = 1.0f / dch[t];
}

// helper: 4 forward rotation passes on (v0,v1) held across the wave (128-group)
#define FWD_ROT(tl, v0, v1)                                                     \
  _Pragma("unroll")                                                             \
  for (int r = 0; r < NROT; ++r) {                                              \
    const float4 e0 = tl[r * 128 + l];                                          \
    const float4 e1 = tl[r * 128 + 64 + l];                                     \
    const int p0 = __float_as_int(e0.z), p1 = __float_as_int(e1.z);             \
    const int a0 = (p0 & 63) << 2, a1 = (p1 & 63) << 2;                         \
    _Pragma("unroll")                                                           \
    for (int q = 0; q < 4; ++q) {                                               \
      const int x0 = __float_as_int(v0[q]), x1 = __float_as_int(v1[q]);         \
      const float lo0 = __int_as_float(__builtin_amdgcn_ds_bpermute(a0, x0));   \
      const float hi0 = __int_as_float(__builtin_amdgcn_ds_bpermute(a0, x1));   \
      const float lo1 = __int_as_float(__builtin_amdgcn_ds_bpermute(a1, x0));   \
      const float hi1 = __int_as_float(__builtin_amdgcn_ds_bpermute(a1, x1));   \
      const float op0 = (p0 & 64) ? hi0 : lo0;                                  \
      const float op1 = (p1 & 64) ? hi1 : lo1;                                  \
      {                                                                         \
        _Pragma("clang fp contract(off)")                                       \
        v0[q] = e0.x * v0[q] + e0.y * op0;                                      \
        v1[q] = e1.x * v1[q] + e1.y * op1;                                      \
      }                                                                         \
    }                                                                           \
  }

// ---------------- weight pseudo-quantize (forward only, outputs rotated q) ------
__global__ __launch_bounds__(256) void k_quant(
    const float* __restrict__ W, const float4* __restrict__ tbl,
    const float* __restrict__ ch, unsigned short* __restrict__ out, int In, int G) {
  __shared__ float4 tl[NROT * 128];
  const int wv = threadIdx.x >> 6, l = threadIdx.x & 63;
  const int g = blockIdx.x % G;
  const int rowblk = blockIdx.x / G;
  const int row0 = rowblk * 16 + wv * 4;
  const int colbase = g << 7;
  tl[threadIdx.x]       = tbl[(size_t)g * NROT * 128 + threadIdx.x];
  tl[256 + threadIdx.x] = tbl[(size_t)g * NROT * 128 + 256 + threadIdx.x];
  __syncthreads();
  const float c0 = ch[colbase + l], c1 = ch[colbase + 64 + l];
  float v0[4], v1[4];
#pragma unroll
  for (int q = 0; q < 4; ++q) {
#pragma clang fp contract(off)
    const float* Wr = W + (size_t)(row0 + q) * In + colbase;
    v0[q] = Wr[l] * c0;
    v1[q] = Wr[64 + l] * c1;
  }
  FWD_ROT(tl, v0, v1)
  // fake quant per row; output stays in rotated space
#pragma unroll
  for (int q = 0; q < 4; ++q) {
    float mn = fminf(v0[q], v1[q]), mx = fmaxf(v0[q], v1[q]);
#pragma unroll
    for (int o = 32; o > 0; o >>= 1) {
      mn = fminf(mn, __shfl_xor(mn, o));
      mx = fmaxf(mx, __shfl_xor(mx, o));
    }
    {
#pragma clang fp contract(off)
      const float scale = fmaxf(mx - mn, 1e-5f) / 15.0f;
      const float zero = rintf(-mn / scale);
      const float q0 = fminf(fmaxf(rintf(v0[q] / scale) + zero, 0.0f), 15.0f);
      const float q1 = fminf(fmaxf(rintf(v1[q] / scale) + zero, 0.0f), 15.0f);
      v0[q] = (q0 - zero) * scale;
      v1[q] = (q1 - zero) * scale;
    }
  }
#pragma unroll
  for (int q = 0; q < 4; ++q) {
    unsigned short* Or = out + (size_t)(row0 + q) * In + colbase;
    Or[l]      = f2bf(v0[q]);
    Or[64 + l] = f2bf(v1[q]);
  }
}

// ---------------- x' = R(x / ch) -> bf16 ----------------
__global__ __launch_bounds__(256) void k_rotx(
    const float* __restrict__ X, const float* __restrict__ rch,
    const float4* __restrict__ tbl, unsigned short* __restrict__ out) {
  __shared__ float4 tl[NROT * 128];
  const int wv = threadIdx.x >> 6, l = threadIdx.x & 63;
  const int g = blockIdx.x % 16;                 // HIDDEN/128 groups
  const int rowblk = blockIdx.x / 16;
  const int row0 = rowblk * 16 + wv * 4;
  const int colbase = g << 7;
  tl[threadIdx.x]       = tbl[(size_t)g * NROT * 128 + threadIdx.x];
  tl[256 + threadIdx.x] = tbl[(size_t)g * NROT * 128 + 256 + threadIdx.x];
  __syncthreads();
  const float i0 = rch[colbase + l], i1 = rch[colbase + 64 + l];
  float v0[4], v1[4];
#pragma unroll
  for (int q = 0; q < 4; ++q) {
    const float* Xr = X + (size_t)(row0 + q) * HIDDEN + colbase;
    v0[q] = Xr[l] * i0;
    v1[q] = Xr[64 + l] * i1;
  }
  FWD_ROT(tl, v0, v1)
#pragma unroll
  for (int q = 0; q < 4; ++q) {
    unsigned short* Or = out + (size_t)(row0 + q) * HIDDEN + colbase;
    Or[l]      = f2bf(v0[q]);
    Or[64 + l] = f2bf(v1[q]);
  }
}

// ---------------- inter' = R_d( silu(gate)*up*wgt / ch_d ) -> bf16 ----------------
__global__ __launch_bounds__(256) void k_silu2(
    const float* __restrict__ h, const float* __restrict__ pw,
    const float* __restrict__ rch, const float4* __restrict__ tbl,
    unsigned short* __restrict__ out) {
  __shared__ float4 tl[NROT * 128];
  const int wv = threadIdx.x >> 6, l = threadIdx.x & 63;
  const int g = blockIdx.x % 6;                  // INTERM/128 groups
  const int rowblk = blockIdx.x / 6;
  const int row0 = rowblk * 16 + wv * 4;
  const int colbase = g << 7;
  tl[threadIdx.x]       = tbl[(size_t)g * NROT * 128 + threadIdx.x];
  tl[256 + threadIdx.x] = tbl[(size_t)g * NROT * 128 + 256 + threadIdx.x];
  __syncthreads();
  const float i0 = rch[colbase + l], i1 = rch[colbase + 64 + l];
  float v0[4], v1[4];
#pragma unroll
  for (int q = 0; q < 4; ++q) {
    const int row = row0 + q;
    const float wgt = pw[row];
    const float* hr = h + (size_t)row * 1536 + colbase;
    const float g0 = hr[l], g1 = hr[64 + l];
    const float u0 = hr[768 + l], u1 = hr[768 + 64 + l];
    v0[q] = g0 / (1.0f + expf(-g0)) * u0 * wgt * i0;
    v1[q] = g1 / (1.0f + expf(-g1)) * u1 * wgt * i1;
  }
  FWD_ROT(tl, v0, v1)
#pragma unroll
  for (int q = 0; q < 4; ++q) {
    unsigned short* Or = out + (size_t)(row0 + q) * INTERM + colbase;
    Or[l]      = f2bf(v0[q]);
    Or[64 + l] = f2bf(v1[q]);
  }
}

// ---------------- expert-segmented GEMM: C = A * B^T, dbuf pipeline ----------------
template <int MODE>
__launch_bounds__(256, 4)
__global__ void k_gemm(const unsigned short* __restrict__ A,
                       const unsigned short* __restrict__ Bw,
                       float* __restrict__ C,
                       const int* __restrict__ pt,
                       const int* __restrict__ off,
                       const int* __restrict__ cnt,
                       const int* __restrict__ tmap) {
  constexpr int K = MODE ? INTERM : HIDDEN;
  constexpr int N = MODE ? HIDDEN : 2 * INTERM;
  const int tm = tmap[blockIdx.y];
  if (tm < 0) return;
  const int e = tm >> 16;
  const int m0 = (tm & 0xffff) << 7;
  const int count = cnt[e];
  const int seg = off[e];
  const int n0 = blockIdx.x * 128;
  const unsigned short* Be = Bw + (size_t)e * N * K;

  __shared__ unsigned short As[2][128 * 32];
  __shared__ unsigned short Bs[2][128 * 32];

  const int tid = threadIdx.x;
  const int w = tid >> 6;
  const int l = tid & 63;
  const int r0 = w * 16 + (l >> 2);
  const int r1 = r0 + 64;
  const int kco = (l & 3) * 8;

  int p0 = m0 + r0; if (p0 > count - 1) p0 = count - 1;
  int p1 = m0 + r1; if (p1 > count - 1) p1 = count - 1;
  size_t arow0, arow1;
  if (MODE == 0) { arow0 = pt[seg + p0]; arow1 = pt[seg + p1]; }
  else           { arow0 = (size_t)(seg + p0); arow1 = (size_t)(seg + p1); }
  const unsigned short* pa0 = A + arow0 * K + kco;
  const unsigned short* pa1 = A + arow1 * K + kco;
  const unsigned short* pb0 = Be + (size_t)(n0 + r0) * K + kco;
  const unsigned short* pb1 = Be + (size_t)(n0 + r1) * K + kco;

  const int ko = (l >> 4) * 8;
  const int mrow = (w & 1) * 64 + (l & 15);
  const int nrow = (w >> 1) * 64 + (l & 15);

  f32x4 acc[4][4];
#pragma unroll
  for (int i = 0; i < 4; ++i)
#pragma unroll
    for (int j = 0; j < 4; ++j) acc[i][j] = (f32x4)0.0f;

  {
    async16(pa0, &As[0][w * 512]);
    async16(pa1, &As[0][(w + 4) * 512]);
    async16(pb0, &Bs[0][w * 512]);
    async16(pb1, &Bs[0][(w + 4) * 512]);
  }
  int buf = 0;
  for (int k0 = 0; k0 < K; k0 += 32, buf ^= 1) {
    __syncthreads();               // drains the loads targeting 'buf'
    bf16x8 af[4], bfr[4];
#pragma unroll
    for (int i = 0; i < 4; ++i)
      af[i] = *(const bf16x8*)&As[buf][(mrow + i * 16) * 32 + ko];
#pragma unroll
    for (int j = 0; j < 4; ++j)
      bfr[j] = *(const bf16x8*)&Bs[buf][(nrow + j * 16) * 32 + ko];
    if (k0 + 32 < K) {             // prefetch next tile AFTER the ds_reads
      const int kn = k0 + 32;
      async16(pa0 + kn, &As[buf ^ 1][w * 512]);
      async16(pa1 + kn, &As[buf ^ 1][(w + 4) * 512]);
      async16(pb0 + kn, &Bs[buf ^ 1][w * 512]);
      async16(pb1 + kn, &Bs[buf ^ 1][(w + 4) * 512]);
    }
#pragma unroll
    for (int i = 0; i < 4; ++i)
#pragma unroll
      for (int j = 0; j < 4; ++j)
        acc[i][j] = __builtin_amdgcn_mfma_f32_16x16x32_bf16(af[i], bfr[j], acc[i][j], 0, 0, 0);
  }

  const int mb = (w & 1) * 64 + (l >> 4) * 4;
  const int nb = n0 + (w >> 1) * 64 + (l & 15);
#pragma unroll
  for (int i = 0; i < 4; ++i) {
#pragma unroll
    for (int j = 0; j < 4; ++j) {
#pragma unroll
      for (int r = 0; r < 4; ++r) {
        const int mm = m0 + mb + i * 16 + r;
        if (mm < count) {
          const int nn = nb + j * 16;
          if (MODE == 0) {
            C[(size_t)(seg + mm) * N + nn] = acc[i][j][r];
          } else {
            atomicAdd(&C[(size_t)pt[seg + mm] * N + nn], acc[i][j][r]);
          }
        }
      }
    }
  }
}

// ---------------- launch ----------------
extern "C" void kernel_launch(void* const* d_in, const int* in_sizes, int n_in,
                              void* d_out, int out_size, void* d_ws, size_t ws_size,
                              hipStream_t stream) {
  const float* hs  = (const float*)d_in[0];
  const int*   tki = (const int*)d_in[1];
  const float* tkw = (const float*)d_in[2];
  const float* guw = (const float*)d_in[3];
  const float* dww = (const float*)d_in[4];
  const int*   gupr= (const int*)d_in[5];
  const float* gua = (const float*)d_in[6];
  const int*   dwp = (const int*)d_in[7];
  const float* dwa = (const float*)d_in[8];
  const float* gus = (const float*)d_in[9];
  const float* dwsc= (const float*)d_in[10];
  float* out = (float*)d_out;
  char* ws = (char*)d_ws;

  unsigned short* gup_bf = (unsigned short*)(ws + 0);          //  50,331,648 B
  unsigned short* dwn_bf = (unsigned short*)(ws + 50331648);   //  25,165,824 B
  unsigned short* x_bf   = (unsigned short*)(ws + 75497472);   //  16,777,216 B
  float*          hbuf   = (float*)(ws + 92274688);            //  50,331,648 B
  unsigned short* interb = (unsigned short*)(ws + 142606336);  //  12,582,912 B
  int*            pt     = (int*)(ws + 155189248);             //  32,768 B
  float*          pw     = (float*)(ws + 155222016);           //  32,768 B
  int*            cnt    = (int*)(ws + 155254784);             //  cnt/off/cur/tmap (384 B)
  int*            off    = cnt + 8;
  int*            cur    = cnt + 16;
  int*            tmap   = cnt + 24;
  float4*         tg     = (float4*)(ws + 155258880);          // 131,072 B (16 grp)
  float4*         td     = (float4*)(ws + 155389952);          //  49,152 B (6 grp)
  float*          grch   = (float*)(ws + 155439104);           //   8,192 B
  float*          drch   = (float*)(ws + 155447296);           //   3,072 B

  (void)hipMemsetAsync(d_out, 0, (size_t)T_TOKENS * HIDDEN * sizeof(float), stream);
  (void)hipMemsetAsync(cnt, 0, 32, stream);

  k_hist<<<32, 256, 0, stream>>>(tki, cnt);
  k_scan<<<1, 64, 0, stream>>>(cnt, off, cur, tmap);
  k_scatter<<<32, 256, 0, stream>>>(tki, tkw, off, cur, pt, pw);
  k_tbl<<<16, 256, 0, stream>>>(gupr, gua, dwp, dwa, gus, dwsc, tg, td, grch, drch);
  k_rotx<<<4096, 256, 0, stream>>>(hs, grch, tg, x_bf);
  k_quant<<<12288, 256, 0, stream>>>(guw, tg, gus, gup_bf, HIDDEN, 16);
  k_quant<<<6144, 256, 0, stream>>>(dww, td, dwsc, dwn_bf, INTERM, 6);
  k_gemm<0><<<dim3(12, MAXT), 256, 0, stream>>>(x_bf, gup_bf, hbuf, pt, off, cnt, tmap);
  k_silu2<<<3072, 256, 0, stream>>>(hbuf, pw, drch, td, interb);
  k_gemm<1><<<dim3(16, MAXT), 256, 0, stream>>>(interb, dwn_bf, out, pt, off, cnt, tmap);
}